// Round 4
// baseline (150.395 us; speedup 1.0000x reference)
//
#include <hip/hip_runtime.h>

#define NB 16
#define NS 8191
#define SP1 8192
#define NE 768
#define HALF 384
#define VPR (NE / 4)    // 192 float4 per row
#define RPB 8           // rows per block

typedef float f32x4 __attribute__((ext_vector_type(4)));

// Kernel 1: per-batch max of pos[b, :, 0] -> maxsec[b] + magic multiplier for
// exact unsigned division by stride = maxsec+1 (valid for d <= 767, s <= 101).
__global__ __launch_bounds__(1024) void maxsec_kernel(const int* __restrict__ pos,
                                                      int* __restrict__ maxsec,
                                                      unsigned* __restrict__ magics) {
    int b = blockIdx.x;
    int t = threadIdx.x;
    const int* p = pos + (size_t)b * NS * 3;
    int m = 0;
    for (int s = t; s < NS; s += 1024) {
        int v = p[s * 3];
        m = v > m ? v : m;
    }
    // wave-level reduce, then LDS across 16 waves
#pragma unroll
    for (int off = 32; off > 0; off >>= 1) {
        int o = __shfl_down(m, off, 64);
        m = o > m ? o : m;
    }
    __shared__ int sm[16];
    if ((t & 63) == 0) sm[t >> 6] = m;
    __syncthreads();
    if (t == 0) {
        int ms = sm[0];
#pragma unroll
        for (int w = 1; w < 16; ++w) ms = sm[w] > ms ? sm[w] : ms;
        maxsec[b] = ms;
        unsigned stride = (unsigned)(ms + 1);
        magics[b] = (0x100000u + stride - 1u) / stride;  // ceil(2^20 / stride)
    }
}

// Kernel 2: out[b,s,:] = x[b,s,:] + pos_embedding + sec
// grid = (SP1/RPB, NB), block = 192 threads, one float4 per thread per row.
__global__ __launch_bounds__(192) void posembed_kernel(const f32x4* __restrict__ x,
                                                       const int* __restrict__ pos,
                                                       const f32x4* __restrict__ pe4,
                                                       const int* __restrict__ maxsec,
                                                       const unsigned* __restrict__ magics,
                                                       f32x4* __restrict__ out) {
    const int b = blockIdx.y;
    const int s0 = blockIdx.x * RPB;
    const int t = threadIdx.x;

    const int ms = maxsec[b];
    const unsigned stride = (unsigned)(ms + 1);
    const unsigned magic = magics[b];

    const size_t base = ((size_t)b * SP1 + s0) * VPR + t;

    // Issue all row loads up front for memory-level parallelism.
    f32x4 xv[RPB];
#pragma unroll
    for (int r = 0; r < RPB; ++r)
        xv[r] = __builtin_nontemporal_load(&x[base + (size_t)r * VPR]);

#pragma unroll
    for (int r = 0; r < RPB; ++r) {
        const int s = s0 + r;
        f32x4 o;
        if (s == 0) {
            o = xv[r];
        } else {
            const int* pr = pos + ((size_t)b * NS + (s - 1)) * 3;
            const int p0 = pr[0];
            const int i1 = pr[1];
            const int i2 = pr[2];

            // positional embedding: one float4 gather (alignment: i*384 floats)
            f32x4 emb = (t < HALF / 4) ? pe4[i1 * (HALF / 4) + t]
                                       : pe4[i2 * (HALF / 4) + (t - HALF / 4)];

            // sec term, flipped along E: element j has d = (767 - 4t - j) - p0
            f32x4 secs = {0.f, 0.f, 0.f, 0.f};
            const int d0 = (NE - 1) - 4 * t - p0;
            if (ms > 0 && d0 >= 0) {
                unsigned ud = (unsigned)d0;
                unsigned m = ud - stride * ((ud * magic) >> 20);  // d0 % stride (exact)
#pragma unroll
                for (int j = 0; j < 4; ++j) {
                    if (d0 - j >= 0 && m == 0u) secs[j] = 1.0f;
                    m = (m == 0u) ? stride - 1u : m - 1u;
                }
            }

            o = xv[r] + emb + secs;
        }
        __builtin_nontemporal_store(o, &out[base + (size_t)r * VPR]);
    }
}

extern "C" void kernel_launch(void* const* d_in, const int* in_sizes, int n_in,
                              void* d_out, int out_size, void* d_ws, size_t ws_size,
                              hipStream_t stream) {
    const float* x   = (const float*)d_in[0];
    const int*   pos = (const int*)d_in[1];
    const float* pe  = (const float*)d_in[2];
    float* out = (float*)d_out;
    int* maxsec = (int*)d_ws;
    unsigned* magics = (unsigned*)((char*)d_ws + NB * sizeof(int));

    maxsec_kernel<<<NB, 1024, 0, stream>>>(pos, maxsec, magics);

    dim3 grid(SP1 / RPB, NB);
    posembed_kernel<<<grid, 192, 0, stream>>>((const f32x4*)x, pos,
                                              (const f32x4*)pe, maxsec, magics,
                                              (f32x4*)out);
}

// Round 5
// 141.163 us; speedup vs baseline: 1.0654x; 1.0654x over previous
//
#include <hip/hip_runtime.h>

#define NB 16
#define NS 8191
#define SP1 8192
#define NE 768
#define HALF 384
#define VPR (NE / 4)    // 192 float4 per row
#define RPB 2           // rows per block

typedef float f32x4 __attribute__((ext_vector_type(4)));

// Kernel 1: per-batch max of pos[b, :, 0] -> maxsec[b] + magic multiplier for
// exact unsigned division by stride = maxsec+1 (valid for d <= 767, s <= 101).
__global__ __launch_bounds__(1024) void maxsec_kernel(const int* __restrict__ pos,
                                                      int* __restrict__ maxsec,
                                                      unsigned* __restrict__ magics) {
    int b = blockIdx.x;
    int t = threadIdx.x;
    const int* p = pos + (size_t)b * NS * 3;
    int m = 0;
    for (int s = t; s < NS; s += 1024) {
        int v = p[s * 3];
        m = v > m ? v : m;
    }
#pragma unroll
    for (int off = 32; off > 0; off >>= 1) {
        int o = __shfl_down(m, off, 64);
        m = o > m ? o : m;
    }
    __shared__ int sm[16];
    if ((t & 63) == 0) sm[t >> 6] = m;
    __syncthreads();
    if (t == 0) {
        int ms = sm[0];
#pragma unroll
        for (int w = 1; w < 16; ++w) ms = sm[w] > ms ? sm[w] : ms;
        maxsec[b] = ms;
        unsigned stride = (unsigned)(ms + 1);
        magics[b] = (0x100000u + stride - 1u) / stride;  // ceil(2^20 / stride)
    }
}

// Kernel 2: out[b,s,:] = x[b,s,:] + pos_embedding + sec
// grid = (SP1/RPB, NB), block = 192 threads, one float4 per thread per row.
__global__ __launch_bounds__(192) void posembed_kernel(const f32x4* __restrict__ x,
                                                       const int* __restrict__ pos,
                                                       const f32x4* __restrict__ pe4,
                                                       const int* __restrict__ maxsec,
                                                       const unsigned* __restrict__ magics,
                                                       f32x4* __restrict__ out) {
    const int b = blockIdx.y;
    const int s0 = blockIdx.x * RPB;
    const int t = threadIdx.x;

    const int ms = maxsec[b];
    const unsigned stride = (unsigned)(ms + 1);
    const unsigned magic = magics[b];

    const size_t base = ((size_t)b * SP1 + s0) * VPR + t;

    // Issue row loads up front for memory-level parallelism.
    f32x4 xv[RPB];
#pragma unroll
    for (int r = 0; r < RPB; ++r)
        xv[r] = __builtin_nontemporal_load(&x[base + (size_t)r * VPR]);

#pragma unroll
    for (int r = 0; r < RPB; ++r) {
        const int s = s0 + r;
        f32x4 o;
        if (s == 0) {
            o = xv[r];
        } else {
            const int* pr = pos + ((size_t)b * NS + (s - 1)) * 3;
            const int p0 = pr[0];
            const int i1 = pr[1];
            const int i2 = pr[2];

            // positional embedding: one float4 gather (alignment: i*384 floats)
            f32x4 emb = (t < HALF / 4) ? pe4[i1 * (HALF / 4) + t]
                                       : pe4[i2 * (HALF / 4) + (t - HALF / 4)];

            // sec term, flipped along E: element j has d = (767 - 4t - j) - p0
            f32x4 secs = {0.f, 0.f, 0.f, 0.f};
            if (ms > 0) {  // batch-uniform branch
                const int d0 = (NE - 1) - 4 * t - p0;
                if (d0 >= 0) {
                    unsigned ud = (unsigned)d0;
                    unsigned m = ud - stride * ((ud * magic) >> 20);  // d0 % stride
#pragma unroll
                    for (int j = 0; j < 4; ++j) {
                        if (d0 - j >= 0 && m == 0u) secs[j] = 1.0f;
                        m = (m == 0u) ? stride - 1u : m - 1u;
                    }
                }
            }

            o = xv[r] + emb + secs;
        }
        __builtin_nontemporal_store(o, &out[base + (size_t)r * VPR]);
    }
}

extern "C" void kernel_launch(void* const* d_in, const int* in_sizes, int n_in,
                              void* d_out, int out_size, void* d_ws, size_t ws_size,
                              hipStream_t stream) {
    const float* x   = (const float*)d_in[0];
    const int*   pos = (const int*)d_in[1];
    const float* pe  = (const float*)d_in[2];
    float* out = (float*)d_out;
    int* maxsec = (int*)d_ws;
    unsigned* magics = (unsigned*)((char*)d_ws + NB * sizeof(int));

    maxsec_kernel<<<NB, 1024, 0, stream>>>(pos, maxsec, magics);

    dim3 grid(SP1 / RPB, NB);
    posembed_kernel<<<grid, 192, 0, stream>>>((const f32x4*)x, pos,
                                              (const f32x4*)pe, maxsec, magics,
                                              (f32x4*)out);
}